// Round 9
// baseline (2005.860 us; speedup 1.0000x reference)
//
#include <hip/hip_runtime.h>
#include <math.h>

// CausalSelfAttention w/ KV cache, MI355X gfx950.
// B=8 T=64 C=2048 H=16 hd=128 S=4096 -> SKV=4160. All device I/O is FLOAT32.
// R9 = FULL ATTRIBUTION ROUND: every kernel carries an idempotent repeat dim
// (same values -> same addresses) sized so each dispatch exceeds the 325us
// harness poison-fills and surfaces in the top-5 WITH counters.
//   qkv x12 (grid.z), attn x4, combine x32 (grid.y), proj x24 (grid.z).
// True per-kernel time = dispatch_dur / NREP. Piggyback: nseg 13->10.

typedef __attribute__((ext_vector_type(4))) float f32x4;
typedef __attribute__((ext_vector_type(8))) short s16x8;
typedef __attribute__((ext_vector_type(4))) short s16x4;
typedef __attribute__((ext_vector_type(2))) unsigned int u32x2;
typedef __attribute__((ext_vector_type(4))) unsigned int u32x4;

#define MFMA_BF16(A_, B_, C_) __builtin_amdgcn_mfma_f32_16x16x32_bf16((A_), (B_), (C_), 0, 0, 0)

__device__ __forceinline__ unsigned short f2bf(float f) {
  unsigned int u = __builtin_bit_cast(unsigned int, f);
  u += 0x7FFFu + ((u >> 16) & 1u);
  return (unsigned short)(u >> 16);
}
__device__ __forceinline__ unsigned int pack2(float a, float b) {
  return (unsigned int)f2bf(a) | ((unsigned int)f2bf(b) << 16);
}
// Barrier with LDS-visibility only: does NOT drain vmcnt.
__device__ __forceinline__ void lds_barrier() {
  asm volatile("s_waitcnt lgkmcnt(0)" ::: "memory");
  __builtin_amdgcn_s_barrier();
}

// ---------------------------------------------------------------------------
// GEMM (body frozen from R8; grid.z = idempotent repeat).
// ---------------------------------------------------------------------------
constexpr float QSCALE = 0.08838834764831845f * 1.4426950408889634f; // 1/sqrt(128)*log2e

template <int BM>
__global__ __launch_bounds__(256) void gemm_kernel(
    const float* __restrict__ A, const float* __restrict__ W,
    int ncols, int mode,
    unsigned short* __restrict__ qws, float* __restrict__ kout,
    float* __restrict__ vout, float* __restrict__ yout)
{
  constexpr int MI = BM / 32;
  constexpr int AIT = BM / 32;
  __shared__ __align__(16) unsigned short Alds[BM][72];
  __shared__ __align__(16) unsigned short Blds[128][72];

  const int tid = threadIdx.x;
  const int w = tid >> 6, l = tid & 63;
  const int lr = l & 15, lg = l >> 4;
  const int n0 = blockIdx.x * 128;
  const int m0 = blockIdx.y * BM;
  const int wm = (w >> 1) * (BM / 2), wn = (w & 1) * 64;

  const int arow = tid >> 3, acol = (tid & 7) << 3;
  const int bkp = tid >> 4, bcol = (tid & 15) << 3;
  const int bswz = ((bcol >> 3) & 7) << 3;

  f32x4 ar[AIT][2];
  f32x4 br[2][4];

  auto loadA = [&](int k0) {
#pragma unroll
    for (int it = 0; it < AIT; ++it) {
      const float* pa = A + (size_t)(m0 + it * 32 + arow) * 2048 + k0 + acol;
      ar[it][0] = *(const f32x4*)pa;
      ar[it][1] = *(const f32x4*)(pa + 4);
    }
  };
  auto loadB = [&](int k0) {
#pragma unroll
    for (int i = 0; i < 2; ++i) {
      const int krow = 2 * (i * 16 + bkp);
      const float* pw = W + (size_t)(k0 + krow) * ncols + n0 + bcol;
      br[i][0] = *(const f32x4*)pw;
      br[i][1] = *(const f32x4*)(pw + 4);
      br[i][2] = *(const f32x4*)(pw + ncols);
      br[i][3] = *(const f32x4*)(pw + ncols + 4);
    }
  };

  f32x4 acc[MI][4] = {};

  loadA(0); loadB(0);
  for (int ks = 0; ks < 32; ++ks) {
#pragma unroll
    for (int it = 0; it < AIT; ++it) {
      u32x4 p;
      p[0] = pack2(ar[it][0][0], ar[it][0][1]); p[1] = pack2(ar[it][0][2], ar[it][0][3]);
      p[2] = pack2(ar[it][1][0], ar[it][1][1]); p[3] = pack2(ar[it][1][2], ar[it][1][3]);
      *(u32x4*)(&Alds[it * 32 + arow][acol]) = p;
    }
#pragma unroll
    for (int i = 0; i < 2; ++i) {
      const int krow = 2 * (i * 16 + bkp);
      const int kc = krow ^ bswz;
#pragma unroll
      for (int j = 0; j < 8; ++j) {
        const float v0 = (j < 4) ? br[i][0][j] : br[i][1][j - 4];
        const float v1 = (j < 4) ? br[i][2][j] : br[i][3][j - 4];
        *(unsigned int*)(&Blds[bcol + j][kc]) = pack2(v0, v1);
      }
    }
    lds_barrier();

    if (ks < 31) { loadA((ks + 1) * 64); loadB((ks + 1) * 64); }

    s16x8 af[MI][2], bfr[4][2];
#pragma unroll
    for (int mi = 0; mi < MI; ++mi)
#pragma unroll
      for (int kk = 0; kk < 2; ++kk)
        af[mi][kk] = *(const s16x8*)(&Alds[wm + mi * 16 + lr][kk * 32 + lg * 8]);
#pragma unroll
    for (int ni = 0; ni < 4; ++ni) {
      const int n = wn + ni * 16 + lr;
      const int nswz = ((n >> 3) & 7) << 3;
#pragma unroll
      for (int kk = 0; kk < 2; ++kk)
        bfr[ni][kk] = *(const s16x8*)(&Blds[n][(kk * 32 + lg * 8) ^ nswz]);
    }
#pragma unroll
    for (int kk = 0; kk < 2; ++kk)
#pragma unroll
      for (int mi = 0; mi < MI; ++mi)
#pragma unroll
        for (int ni = 0; ni < 4; ++ni)
          acc[mi][ni] = MFMA_BF16(af[mi][kk], bfr[ni][kk], acc[mi][ni]);
    lds_barrier();
  }

  if (mode == 0) {
    const int which = n0 >> 11;
    const int h = (n0 >> 7) & 15;
    float* kv = (which == 1) ? kout : vout;
#pragma unroll
    for (int mi = 0; mi < MI; ++mi)
#pragma unroll
      for (int ni = 0; ni < 4; ++ni) {
        const int d = wn + ni * 16 + lr;
#pragma unroll
        for (int r = 0; r < 4; ++r) {
          const int mg = m0 + wm + mi * 16 + lg * 4 + r;
          const int b = mg >> 6, t = mg & 63;
          const float val = acc[mi][ni][r];
          if (which == 0)
            qws[(((size_t)(b * 16 + h) * 64 + t) << 7) + d] = f2bf(val * QSCALE);
          else
            kv[((size_t)(b * 16 + h) * 4160 + 4096 + t) * 128 + d] = val;
        }
      }
  } else {
#pragma unroll
    for (int mi = 0; mi < MI; ++mi)
#pragma unroll
      for (int ni = 0; ni < 4; ++ni) {
        const int n = n0 + wn + ni * 16 + lr;
#pragma unroll
        for (int r = 0; r < 4; ++r) {
          const int mg = m0 + wm + mi * 16 + lg * 4 + r;
          yout[(size_t)mg * 2048 + n] = acc[mi][ni][r];
        }
      }
  }
}

// ---------------------------------------------------------------------------
// Fused KV-cache copy + flash attention (R6 single-prefetch body).
// blockIdx.x = rep-major: inner = blockIdx.x % (nseg*128).
// ---------------------------------------------------------------------------
__global__ __launch_bounds__(256, 4) void attn_kernel(
    const float* __restrict__ pastk, const float* __restrict__ pastv,
    const unsigned short* __restrict__ qws,
    float* __restrict__ kout, float* __restrict__ vout,
    float* __restrict__ Ows, float* __restrict__ mlws,
    int nseg, int seglen, int ntiles)
{
  __shared__ __align__(16) unsigned short Klds[32 * 128];
  __shared__ __align__(16) unsigned short VT[128 * 36];
  __shared__ __align__(16) unsigned short Plds[4 * 16 * 36];

  const int tid = threadIdx.x;
  const int w = tid >> 6, l = tid & 63;
  const int lr = l & 15, lg = l >> 4;
  const int inner = blockIdx.x % (nseg * 128);
  const int bh = inner / nseg;
  const int seg = inner % nseg;
  const int segbase = seg * seglen;

  s16x8 qf[4];
  {
    const unsigned short* qb = qws + ((size_t)bh * 64 + w * 16 + lr) * 128 + lg * 8;
#pragma unroll
    for (int kk = 0; kk < 4; ++kk) qf[kk] = *(const s16x8*)(qb + kk * 32);
  }

  float mrow[4] = {-INFINITY, -INFINITY, -INFINITY, -INFINITY};
  float lrowv[4] = {0.f, 0.f, 0.f, 0.f};
  f32x4 Oacc[8] = {};

  const int skr = tid >> 3;
  const int sd = (tid & 7) << 2;
  const int kswz = (skr & 7) << 3;

  f32x4 kv[4], vv[4];
  int scur = 0; size_t oocur = 0;

  auto load_tile = [&](int t) {
    const int s = segbase + t * 32 + skr;
    const size_t oo = ((size_t)bh * 4160 + s) * 128 + sd;
    scur = s; oocur = oo;
    if (s < 4096) {
      const float* a = pastk + ((size_t)bh * 4096 + s) * 128 + sd;
      const float* b = pastv + ((size_t)bh * 4096 + s) * 128 + sd;
#pragma unroll
      for (int c = 0; c < 4; ++c) { kv[c] = *(const f32x4*)(a + 32 * c); vv[c] = *(const f32x4*)(b + 32 * c); }
    } else {
#pragma unroll
      for (int c = 0; c < 4; ++c) { kv[c] = *(const f32x4*)(kout + oo + 32 * c); vv[c] = *(const f32x4*)(vout + oo + 32 * c); }
    }
  };

  load_tile(0);
  for (int t = 0; t < ntiles; ++t) {
#pragma unroll
    for (int c = 0; c < 4; ++c) {
      const int d0 = sd + 32 * c;
      u32x2 pk;
      pk[0] = pack2(kv[c][0], kv[c][1]);
      pk[1] = pack2(kv[c][2], kv[c][3]);
      *(u32x2*)(&Klds[skr * 128 + (d0 ^ kswz)]) = pk;
#pragma unroll
      for (int e = 0; e < 4; ++e)
        VT[(d0 + e) * 36 + skr] = f2bf(vv[c][e]);
    }
    const bool dostore = (scur < 4096);
    const size_t oost = oocur;
    lds_barrier();

    if (dostore) {
      float* ko = kout + oost; float* vo = vout + oost;
#pragma unroll
      for (int c = 0; c < 4; ++c) { *(f32x4*)(ko + 32 * c) = kv[c]; *(f32x4*)(vo + 32 * c) = vv[c]; }
    }
    if (t + 1 < ntiles) load_tile(t + 1);

    f32x4 sc[2] = {};
#pragma unroll
    for (int kk = 0; kk < 4; ++kk)
#pragma unroll
      for (int st = 0; st < 2; ++st) {
        const int krow = st * 16 + lr;
        s16x8 kf = *(const s16x8*)(&Klds[krow * 128 + ((kk * 32 + lg * 8) ^ ((krow & 7) << 3))]);
        sc[st] = MFMA_BF16(qf[kk], kf, sc[st]);
      }

#pragma unroll
    for (int r = 0; r < 4; ++r) {
      float tm = fmaxf(sc[0][r], sc[1][r]);
      tm = fmaxf(tm, __shfl_xor(tm, 1));
      tm = fmaxf(tm, __shfl_xor(tm, 2));
      tm = fmaxf(tm, __shfl_xor(tm, 4));
      tm = fmaxf(tm, __shfl_xor(tm, 8));
      const float mn = fmaxf(mrow[r], tm);
      const float alpha = exp2f(mrow[r] - mn);
      mrow[r] = mn;
      const float p0f = exp2f(sc[0][r] - mn);
      const float p1f = exp2f(sc[1][r] - mn);
      float rs = p0f + p1f;
      rs += __shfl_xor(rs, 1);
      rs += __shfl_xor(rs, 2);
      rs += __shfl_xor(rs, 4);
      rs += __shfl_xor(rs, 8);
      lrowv[r] = lrowv[r] * alpha + rs;
#pragma unroll
      for (int dt = 0; dt < 8; ++dt) Oacc[dt][r] *= alpha;
      Plds[w * 576 + (lg * 4 + r) * 36 + lr] = f2bf(p0f);
      Plds[w * 576 + (lg * 4 + r) * 36 + 16 + lr] = f2bf(p1f);
    }

    const s16x4 plo = *(const s16x4*)(&Plds[w * 576 + lr * 36 + lg * 8]);
    const s16x4 phi = *(const s16x4*)(&Plds[w * 576 + lr * 36 + lg * 8 + 4]);
    const s16x8 pf = __builtin_shufflevector(plo, phi, 0, 1, 2, 3, 4, 5, 6, 7);
#pragma unroll
    for (int dt = 0; dt < 8; ++dt) {
      const int d = dt * 16 + lr;
      const s16x4 vlo = *(const s16x4*)(&VT[d * 36 + lg * 8]);
      const s16x4 vhi = *(const s16x4*)(&VT[d * 36 + lg * 8 + 4]);
      const s16x8 vf = __builtin_shufflevector(vlo, vhi, 0, 1, 2, 3, 4, 5, 6, 7);
      Oacc[dt] = MFMA_BF16(pf, vf, Oacc[dt]);
    }
    lds_barrier();
  }

  const size_t rowbase = ((size_t)seg * 128 + bh) * 64 + w * 16;
#pragma unroll
  for (int dt = 0; dt < 8; ++dt)
#pragma unroll
    for (int r = 0; r < 4; ++r)
      Ows[(rowbase + lg * 4 + r) * 128 + dt * 16 + lr] = Oacc[dt][r];
  if (lr == 0) {
#pragma unroll
    for (int r = 0; r < 4; ++r) {
      const size_t mi = rowbase + lg * 4 + r;
      mlws[mi * 2 + 0] = mrow[r];
      mlws[mi * 2 + 1] = lrowv[r];
    }
  }
}

// ---------------------------------------------------------------------------
// Merge NSEG partials -> yhead. grid.y = idempotent repeat.
// ---------------------------------------------------------------------------
template <int NSEG>
__global__ __launch_bounds__(256) void combine_kernel(
    const float* __restrict__ Ows, const float* __restrict__ mlws,
    float* __restrict__ yhead)
{
  const int idx = blockIdx.x * 256 + threadIdx.x;
  const int d4 = (idx & 31) << 2;
  const int row = idx >> 5;
  float M = -INFINITY;
#pragma unroll
  for (int s = 0; s < NSEG; ++s) M = fmaxf(M, mlws[((size_t)s * 8192 + row) * 2]);
  f32x4 num = {0.f, 0.f, 0.f, 0.f};
  float den = 0.f;
#pragma unroll
  for (int s = 0; s < NSEG; ++s) {
    const size_t r = (size_t)s * 8192 + row;
    const float wgt = exp2f(mlws[r * 2] - M);
    den += wgt * mlws[r * 2 + 1];
    const f32x4 o4 = *(const f32x4*)(Ows + r * 128 + d4);
#pragma unroll
    for (int e = 0; e < 4; ++e) num[e] += wgt * o4[e];
  }
  const float inv = 1.0f / den;
  const int bh = row >> 6, q = row & 63;
  const int b = bh >> 4, h = bh & 15;
  float* yp = yhead + (size_t)(b * 64 + q) * 2048 + h * 128 + d4;
#pragma unroll
  for (int e = 0; e < 4; ++e) yp[e] = num[e] * inv;
}

// ---------------------------------------------------------------------------
extern "C" void kernel_launch(void* const* d_in, const int* in_sizes, int n_in,
                              void* d_out, int out_size, void* d_ws, size_t ws_size,
                              hipStream_t stream)
{
  (void)in_sizes; (void)n_in; (void)out_size;
  const float* x  = (const float*)d_in[0];
  const float* pk = (const float*)d_in[1];
  const float* pv = (const float*)d_in[2];
  const float* wa = (const float*)d_in[3];
  const float* wp = (const float*)d_in[4];

  float* out  = (float*)d_out;
  float* y    = out;                          // 1,048,576
  float* kout = out + 1048576;                // 68,157,440
  float* vout = out + 1048576 + 68157440;     // 68,157,440

  char* ws = (char*)d_ws;
  unsigned short* qws = (unsigned short*)(ws);                      // 2 MiB bf16
  float* yhead = (float*)(ws + ((size_t)2 << 20));                  // 4 MiB f32
  float* mlws  = (float*)(ws + ((size_t)6 << 20));                  // 640 KiB
  float* Ows   = (float*)(ws + ((size_t)7 << 20));                  // nseg*4 MiB

  const size_t base = (size_t)7 << 20;
  int nseg = 1;
  if (ws_size >= base + (size_t)10 * 4194304) nseg = 10;     // 1280 blocks, 5/CU
  else if (ws_size >= base + (size_t)5 * 4194304) nseg = 5;
  const int seglen = 4160 / nseg;   // 416 / 832 / 4160
  const int ntiles = seglen / 32;

  // Attribution repeats (idempotent; remove in R10):
  const int R_QKV = 12, R_ATTN = 4, R_CMB = 32, R_PROJ = 24;

  gemm_kernel<32><<<dim3(48, 16, R_QKV), dim3(256), 0, stream>>>(x, wa, 6144, 0, qws, kout, vout, nullptr);
  attn_kernel<<<dim3(128 * nseg * R_ATTN), dim3(256), 0, stream>>>(pk, pv, qws, kout, vout, Ows, mlws,
                                                                   nseg, seglen, ntiles);
  if (nseg == 10)     combine_kernel<10><<<dim3(1024, R_CMB), dim3(256), 0, stream>>>(Ows, mlws, yhead);
  else if (nseg == 5) combine_kernel<5><<<dim3(1024, R_CMB), dim3(256), 0, stream>>>(Ows, mlws, yhead);
  else                combine_kernel<1><<<dim3(1024, R_CMB), dim3(256), 0, stream>>>(Ows, mlws, yhead);
  gemm_kernel<32><<<dim3(16, 16, R_PROJ), dim3(256), 0, stream>>>(yhead, wp, 2048, 1, nullptr, nullptr, nullptr, y);
}

// Round 10
// 455.740 us; speedup vs baseline: 4.4013x; 4.4013x over previous
//
#include <hip/hip_runtime.h>
#include <math.h>

// CausalSelfAttention w/ KV cache, MI355X gfx950.
// B=8 T=64 C=2048 H=16 hd=128 S=4096 -> SKV=4160. All device I/O is FLOAT32.
// Internals: bf16 MFMA (16x16x32), f32 accumulate.
// R10: THE vmcnt-drain fix. In R2-R9 the copy stores were always issued
// before the next tile's loads, so each convert's wait-for-loads was
// vmcnt(0) = full store drain per tile (the stubborn 4.1 TB/s convoy).
// Now: two reg sets, loads(t+1) issued BEFORE stores(t) (sched_barrier
// pins order) -> counted vmcnt, stores float. Tail reads via separate
// __restrict__ ktail/vtail; stores unconditional (idempotent tail rewrite).

typedef __attribute__((ext_vector_type(4))) float f32x4;
typedef __attribute__((ext_vector_type(8))) short s16x8;
typedef __attribute__((ext_vector_type(4))) short s16x4;
typedef __attribute__((ext_vector_type(2))) unsigned int u32x2;
typedef __attribute__((ext_vector_type(4))) unsigned int u32x4;

#define MFMA_BF16(A_, B_, C_) __builtin_amdgcn_mfma_f32_16x16x32_bf16((A_), (B_), (C_), 0, 0, 0)

__device__ __forceinline__ unsigned short f2bf(float f) {
  unsigned int u = __builtin_bit_cast(unsigned int, f);
  u += 0x7FFFu + ((u >> 16) & 1u);
  return (unsigned short)(u >> 16);
}
__device__ __forceinline__ unsigned int pack2(float a, float b) {
  return (unsigned int)f2bf(a) | ((unsigned int)f2bf(b) << 16);
}
// Barrier with LDS-visibility only: does NOT drain vmcnt.
__device__ __forceinline__ void lds_barrier() {
  asm volatile("s_waitcnt lgkmcnt(0)" ::: "memory");
  __builtin_amdgcn_s_barrier();
}

// ---------------------------------------------------------------------------
// GEMM (frozen from R9). BM x 128 tile, 4 waves, k-step 64, reg prefetch.
// ---------------------------------------------------------------------------
constexpr float QSCALE = 0.08838834764831845f * 1.4426950408889634f; // 1/sqrt(128)*log2e

template <int BM>
__global__ __launch_bounds__(256) void gemm_kernel(
    const float* __restrict__ A, const float* __restrict__ W,
    int ncols, int mode,
    unsigned short* __restrict__ qws, float* __restrict__ kout,
    float* __restrict__ vout, float* __restrict__ yout)
{
  constexpr int MI = BM / 32;
  constexpr int AIT = BM / 32;
  __shared__ __align__(16) unsigned short Alds[BM][72];
  __shared__ __align__(16) unsigned short Blds[128][72];

  const int tid = threadIdx.x;
  const int w = tid >> 6, l = tid & 63;
  const int lr = l & 15, lg = l >> 4;
  const int n0 = blockIdx.x * 128;
  const int m0 = blockIdx.y * BM;
  const int wm = (w >> 1) * (BM / 2), wn = (w & 1) * 64;

  const int arow = tid >> 3, acol = (tid & 7) << 3;
  const int bkp = tid >> 4, bcol = (tid & 15) << 3;
  const int bswz = ((bcol >> 3) & 7) << 3;

  f32x4 ar[AIT][2];
  f32x4 br[2][4];

  auto loadA = [&](int k0) {
#pragma unroll
    for (int it = 0; it < AIT; ++it) {
      const float* pa = A + (size_t)(m0 + it * 32 + arow) * 2048 + k0 + acol;
      ar[it][0] = *(const f32x4*)pa;
      ar[it][1] = *(const f32x4*)(pa + 4);
    }
  };
  auto loadB = [&](int k0) {
#pragma unroll
    for (int i = 0; i < 2; ++i) {
      const int krow = 2 * (i * 16 + bkp);
      const float* pw = W + (size_t)(k0 + krow) * ncols + n0 + bcol;
      br[i][0] = *(const f32x4*)pw;
      br[i][1] = *(const f32x4*)(pw + 4);
      br[i][2] = *(const f32x4*)(pw + ncols);
      br[i][3] = *(const f32x4*)(pw + ncols + 4);
    }
  };

  f32x4 acc[MI][4] = {};

  loadA(0); loadB(0);
  for (int ks = 0; ks < 32; ++ks) {
#pragma unroll
    for (int it = 0; it < AIT; ++it) {
      u32x4 p;
      p[0] = pack2(ar[it][0][0], ar[it][0][1]); p[1] = pack2(ar[it][0][2], ar[it][0][3]);
      p[2] = pack2(ar[it][1][0], ar[it][1][1]); p[3] = pack2(ar[it][1][2], ar[it][1][3]);
      *(u32x4*)(&Alds[it * 32 + arow][acol]) = p;
    }
#pragma unroll
    for (int i = 0; i < 2; ++i) {
      const int krow = 2 * (i * 16 + bkp);
      const int kc = krow ^ bswz;
#pragma unroll
      for (int j = 0; j < 8; ++j) {
        const float v0 = (j < 4) ? br[i][0][j] : br[i][1][j - 4];
        const float v1 = (j < 4) ? br[i][2][j] : br[i][3][j - 4];
        *(unsigned int*)(&Blds[bcol + j][kc]) = pack2(v0, v1);
      }
    }
    lds_barrier();

    if (ks < 31) { loadA((ks + 1) * 64); loadB((ks + 1) * 64); }

    s16x8 af[MI][2], bfr[4][2];
#pragma unroll
    for (int mi = 0; mi < MI; ++mi)
#pragma unroll
      for (int kk = 0; kk < 2; ++kk)
        af[mi][kk] = *(const s16x8*)(&Alds[wm + mi * 16 + lr][kk * 32 + lg * 8]);
#pragma unroll
    for (int ni = 0; ni < 4; ++ni) {
      const int n = wn + ni * 16 + lr;
      const int nswz = ((n >> 3) & 7) << 3;
#pragma unroll
      for (int kk = 0; kk < 2; ++kk)
        bfr[ni][kk] = *(const s16x8*)(&Blds[n][(kk * 32 + lg * 8) ^ nswz]);
    }
#pragma unroll
    for (int kk = 0; kk < 2; ++kk)
#pragma unroll
      for (int mi = 0; mi < MI; ++mi)
#pragma unroll
        for (int ni = 0; ni < 4; ++ni)
          acc[mi][ni] = MFMA_BF16(af[mi][kk], bfr[ni][kk], acc[mi][ni]);
    lds_barrier();
  }

  if (mode == 0) {
    const int which = n0 >> 11;
    const int h = (n0 >> 7) & 15;
    float* kv = (which == 1) ? kout : vout;
#pragma unroll
    for (int mi = 0; mi < MI; ++mi)
#pragma unroll
      for (int ni = 0; ni < 4; ++ni) {
        const int d = wn + ni * 16 + lr;
#pragma unroll
        for (int r = 0; r < 4; ++r) {
          const int mg = m0 + wm + mi * 16 + lg * 4 + r;
          const int b = mg >> 6, t = mg & 63;
          const float val = acc[mi][ni][r];
          if (which == 0)
            qws[(((size_t)(b * 16 + h) * 64 + t) << 7) + d] = f2bf(val * QSCALE);
          else
            kv[((size_t)(b * 16 + h) * 4160 + 4096 + t) * 128 + d] = val;
        }
      }
  } else {
#pragma unroll
    for (int mi = 0; mi < MI; ++mi)
#pragma unroll
      for (int ni = 0; ni < 4; ++ni) {
        const int n = n0 + wn + ni * 16 + lr;
#pragma unroll
        for (int r = 0; r < 4; ++r) {
          const int mg = m0 + wm + mi * 16 + lg * 4 + r;
          yout[(size_t)mg * 2048 + n] = acc[mi][ni][r];
        }
      }
  }
}

// ---------------------------------------------------------------------------
// Fused KV-cache copy + flash attention.
// Per tile phase: convert(cur) [counted vmcnt] | barrier | loads(next, other
// set) FIRST | sched_barrier | stores(cur) | compute | barrier.
// ---------------------------------------------------------------------------
__global__ __launch_bounds__(256, 4) void attn_kernel(
    const float* __restrict__ pastk, const float* __restrict__ pastv,
    const float* __restrict__ ktail, const float* __restrict__ vtail,
    const unsigned short* __restrict__ qws,
    float* __restrict__ kout, float* __restrict__ vout,
    float* __restrict__ Ows, float* __restrict__ mlws,
    int nseg, int seglen, int ntiles)
{
  __shared__ __align__(16) unsigned short Klds[32 * 128];
  __shared__ __align__(16) unsigned short VT[128 * 36];
  __shared__ __align__(16) unsigned short Plds[4 * 16 * 36];

  const int tid = threadIdx.x;
  const int w = tid >> 6, l = tid & 63;
  const int lr = l & 15, lg = l >> 4;
  const int bh = blockIdx.x / nseg;
  const int seg = blockIdx.x % nseg;
  const int segbase = seg * seglen;

  s16x8 qf[4];
  {
    const unsigned short* qb = qws + ((size_t)bh * 64 + w * 16 + lr) * 128 + lg * 8;
#pragma unroll
    for (int kk = 0; kk < 4; ++kk) qf[kk] = *(const s16x8*)(qb + kk * 32);
  }

  float mrow[4] = {-INFINITY, -INFINITY, -INFINITY, -INFINITY};
  float lrowv[4] = {0.f, 0.f, 0.f, 0.f};
  f32x4 Oacc[8] = {};

  const int skr = tid >> 3;        // key row in tile (0..31)
  const int sd = (tid & 7) << 2;   // lane covers floats sd+32c+{0..3}
  const int kswz = (skr & 7) << 3;

  f32x4 kvA[4], vvA[4], kvB[4], vvB[4];
  size_t oA = 0, oB = 0;

  auto load_tile = [&](int t, f32x4 (&kv)[4], f32x4 (&vv)[4], size_t& oor) {
    const int s = segbase + t * 32 + skr;
    const size_t oo = ((size_t)bh * 4160 + s) * 128 + sd;
    oor = oo;
    if (s < 4096) {
      const float* a = pastk + ((size_t)bh * 4096 + s) * 128 + sd;
      const float* b = pastv + ((size_t)bh * 4096 + s) * 128 + sd;
#pragma unroll
      for (int c = 0; c < 4; ++c) { kv[c] = *(const f32x4*)(a + 32 * c); vv[c] = *(const f32x4*)(b + 32 * c); }
    } else {
#pragma unroll
      for (int c = 0; c < 4; ++c) { kv[c] = *(const f32x4*)(ktail + oo + 32 * c); vv[c] = *(const f32x4*)(vtail + oo + 32 * c); }
    }
  };
  auto convert_tile = [&](const f32x4 (&kv)[4], const f32x4 (&vv)[4]) {
#pragma unroll
    for (int c = 0; c < 4; ++c) {
      const int d0 = sd + 32 * c;
      u32x2 pk;
      pk[0] = pack2(kv[c][0], kv[c][1]);
      pk[1] = pack2(kv[c][2], kv[c][3]);
      *(u32x2*)(&Klds[skr * 128 + (d0 ^ kswz)]) = pk;
#pragma unroll
      for (int e = 0; e < 4; ++e)
        VT[(d0 + e) * 36 + skr] = f2bf(vv[c][e]);
    }
  };
  auto copy_store = [&](const f32x4 (&kv)[4], const f32x4 (&vv)[4], size_t oo) {
    float* ko = kout + oo; float* vo = vout + oo;
#pragma unroll
    for (int c = 0; c < 4; ++c) { *(f32x4*)(ko + 32 * c) = kv[c]; *(f32x4*)(vo + 32 * c) = vv[c]; }
  };
  auto compute_tile = [&]() {
    f32x4 sc[2] = {};
#pragma unroll
    for (int kk = 0; kk < 4; ++kk)
#pragma unroll
      for (int st = 0; st < 2; ++st) {
        const int krow = st * 16 + lr;
        s16x8 kf = *(const s16x8*)(&Klds[krow * 128 + ((kk * 32 + lg * 8) ^ ((krow & 7) << 3))]);
        sc[st] = MFMA_BF16(qf[kk], kf, sc[st]);
      }
#pragma unroll
    for (int r = 0; r < 4; ++r) {
      float tm = fmaxf(sc[0][r], sc[1][r]);
      tm = fmaxf(tm, __shfl_xor(tm, 1));
      tm = fmaxf(tm, __shfl_xor(tm, 2));
      tm = fmaxf(tm, __shfl_xor(tm, 4));
      tm = fmaxf(tm, __shfl_xor(tm, 8));
      const float mn = fmaxf(mrow[r], tm);
      const float alpha = exp2f(mrow[r] - mn);
      mrow[r] = mn;
      const float p0f = exp2f(sc[0][r] - mn);
      const float p1f = exp2f(sc[1][r] - mn);
      float rs = p0f + p1f;
      rs += __shfl_xor(rs, 1);
      rs += __shfl_xor(rs, 2);
      rs += __shfl_xor(rs, 4);
      rs += __shfl_xor(rs, 8);
      lrowv[r] = lrowv[r] * alpha + rs;
#pragma unroll
      for (int dt = 0; dt < 8; ++dt) Oacc[dt][r] *= alpha;
      Plds[w * 576 + (lg * 4 + r) * 36 + lr] = f2bf(p0f);
      Plds[w * 576 + (lg * 4 + r) * 36 + 16 + lr] = f2bf(p1f);
    }
    const s16x4 plo = *(const s16x4*)(&Plds[w * 576 + lr * 36 + lg * 8]);
    const s16x4 phi = *(const s16x4*)(&Plds[w * 576 + lr * 36 + lg * 8 + 4]);
    const s16x8 pf = __builtin_shufflevector(plo, phi, 0, 1, 2, 3, 4, 5, 6, 7);
#pragma unroll
    for (int dt = 0; dt < 8; ++dt) {
      const int d = dt * 16 + lr;
      const s16x4 vlo = *(const s16x4*)(&VT[d * 36 + lg * 8]);
      const s16x4 vhi = *(const s16x4*)(&VT[d * 36 + lg * 8 + 4]);
      const s16x8 vf = __builtin_shufflevector(vlo, vhi, 0, 1, 2, 3, 4, 5, 6, 7);
      Oacc[dt] = MFMA_BF16(pf, vf, Oacc[dt]);
    }
  };

  load_tile(0, kvA, vvA, oA);
  for (int t = 0; t < ntiles; t += 2) {
    // ---- tile t (set A)
    convert_tile(kvA, vvA);            // counted vmcnt wait on loads(A)
    lds_barrier();
    if (t + 1 < ntiles) load_tile(t + 1, kvB, vvB, oB);  // loads FIRST
    __builtin_amdgcn_sched_barrier(0);
    copy_store(kvA, vvA, oA);          // stores AFTER -> they float
    compute_tile();
    lds_barrier();
    // ---- tile t+1 (set B)
    if (t + 1 < ntiles) {
      convert_tile(kvB, vvB);          // vmcnt(#stores) - no drain
      lds_barrier();
      if (t + 2 < ntiles) load_tile(t + 2, kvA, vvA, oA); // WAR w/ stores(A,t): 1 phase old
      __builtin_amdgcn_sched_barrier(0);
      copy_store(kvB, vvB, oB);
      compute_tile();
      lds_barrier();
    }
  }

  const size_t rowbase = ((size_t)seg * 128 + bh) * 64 + w * 16;
#pragma unroll
  for (int dt = 0; dt < 8; ++dt)
#pragma unroll
    for (int r = 0; r < 4; ++r)
      Ows[(rowbase + lg * 4 + r) * 128 + dt * 16 + lr] = Oacc[dt][r];
  if (lr == 0) {
#pragma unroll
    for (int r = 0; r < 4; ++r) {
      const size_t mi = rowbase + lg * 4 + r;
      mlws[mi * 2 + 0] = mrow[r];
      mlws[mi * 2 + 1] = lrowv[r];
    }
  }
}

// ---------------------------------------------------------------------------
// Merge NSEG partials -> yhead (frozen from R9).
// ---------------------------------------------------------------------------
template <int NSEG>
__global__ __launch_bounds__(256) void combine_kernel(
    const float* __restrict__ Ows, const float* __restrict__ mlws,
    float* __restrict__ yhead)
{
  const int idx = blockIdx.x * 256 + threadIdx.x;
  const int d4 = (idx & 31) << 2;
  const int row = idx >> 5;
  float M = -INFINITY;
#pragma unroll
  for (int s = 0; s < NSEG; ++s) M = fmaxf(M, mlws[((size_t)s * 8192 + row) * 2]);
  f32x4 num = {0.f, 0.f, 0.f, 0.f};
  float den = 0.f;
#pragma unroll
  for (int s = 0; s < NSEG; ++s) {
    const size_t r = (size_t)s * 8192 + row;
    const float wgt = exp2f(mlws[r * 2] - M);
    den += wgt * mlws[r * 2 + 1];
    const f32x4 o4 = *(const f32x4*)(Ows + r * 128 + d4);
#pragma unroll
    for (int e = 0; e < 4; ++e) num[e] += wgt * o4[e];
  }
  const float inv = 1.0f / den;
  const int bh = row >> 6, q = row & 63;
  const int b = bh >> 4, h = bh & 15;
  float* yp = yhead + (size_t)(b * 64 + q) * 2048 + h * 128 + d4;
#pragma unroll
  for (int e = 0; e < 4; ++e) yp[e] = num[e] * inv;
}

// ---------------------------------------------------------------------------
extern "C" void kernel_launch(void* const* d_in, const int* in_sizes, int n_in,
                              void* d_out, int out_size, void* d_ws, size_t ws_size,
                              hipStream_t stream)
{
  (void)in_sizes; (void)n_in; (void)out_size;
  const float* x  = (const float*)d_in[0];
  const float* pk = (const float*)d_in[1];
  const float* pv = (const float*)d_in[2];
  const float* wa = (const float*)d_in[3];
  const float* wp = (const float*)d_in[4];

  float* out  = (float*)d_out;
  float* y    = out;                          // 1,048,576
  float* kout = out + 1048576;                // 68,157,440
  float* vout = out + 1048576 + 68157440;     // 68,157,440

  char* ws = (char*)d_ws;
  unsigned short* qws = (unsigned short*)(ws);                      // 2 MiB bf16
  float* yhead = (float*)(ws + ((size_t)2 << 20));                  // 4 MiB f32
  float* mlws  = (float*)(ws + ((size_t)6 << 20));                  // 640 KiB
  float* Ows   = (float*)(ws + ((size_t)7 << 20));                  // nseg*4 MiB

  const size_t base = (size_t)7 << 20;
  int nseg = 1;
  if (ws_size >= base + (size_t)10 * 4194304) nseg = 10;     // 1280 blocks, 5/CU
  else if (ws_size >= base + (size_t)5 * 4194304) nseg = 5;
  const int seglen = 4160 / nseg;   // 416 / 832 / 4160
  const int ntiles = seglen / 32;

  gemm_kernel<32><<<dim3(48, 16), dim3(256), 0, stream>>>(x, wa, 6144, 0, qws, kout, vout, nullptr);
  attn_kernel<<<dim3(128 * nseg), dim3(256), 0, stream>>>(pk, pv, kout, vout, qws, kout, vout,
                                                          Ows, mlws, nseg, seglen, ntiles);
  if (nseg == 10)     combine_kernel<10><<<dim3(1024), dim3(256), 0, stream>>>(Ows, mlws, yhead);
  else if (nseg == 5) combine_kernel<5><<<dim3(1024), dim3(256), 0, stream>>>(Ows, mlws, yhead);
  else                combine_kernel<1><<<dim3(1024), dim3(256), 0, stream>>>(Ows, mlws, yhead);
  gemm_kernel<32><<<dim3(16, 16), dim3(256), 0, stream>>>(yhead, wp, 2048, 1, nullptr, nullptr, nullptr, y);
}

// Round 11
// 370.194 us; speedup vs baseline: 5.4184x; 1.2311x over previous
//
#include <hip/hip_runtime.h>
#include <math.h>

// CausalSelfAttention w/ KV cache, MI355X gfx950.
// B=8 T=64 C=2048 H=16 hd=128 S=4096 -> SKV=4160. All device I/O is FLOAT32.
// Internals: bf16 MFMA (16x16x32), f32 accumulate.
// R11: attn reverted to R9 body (R10's sched_barrier/reorder regressed, m141
// pattern). nseg 10->26 (3328 blocks: more concurrent load-bursts per CU,
// Little's-law lever). GEMMs: depth-2 register ring on the k-loop (the 32
// serial 1-deep waits were ~19us of qkv's 33us). combine<26>.

typedef __attribute__((ext_vector_type(4))) float f32x4;
typedef __attribute__((ext_vector_type(8))) short s16x8;
typedef __attribute__((ext_vector_type(4))) short s16x4;
typedef __attribute__((ext_vector_type(2))) unsigned int u32x2;
typedef __attribute__((ext_vector_type(4))) unsigned int u32x4;

#define MFMA_BF16(A_, B_, C_) __builtin_amdgcn_mfma_f32_16x16x32_bf16((A_), (B_), (C_), 0, 0, 0)

__device__ __forceinline__ unsigned short f2bf(float f) {
  unsigned int u = __builtin_bit_cast(unsigned int, f);
  u += 0x7FFFu + ((u >> 16) & 1u);
  return (unsigned short)(u >> 16);
}
__device__ __forceinline__ unsigned int pack2(float a, float b) {
  return (unsigned int)f2bf(a) | ((unsigned int)f2bf(b) << 16);
}
// Barrier with LDS-visibility only: does NOT drain vmcnt.
__device__ __forceinline__ void lds_barrier() {
  asm volatile("s_waitcnt lgkmcnt(0)" ::: "memory");
  __builtin_amdgcn_s_barrier();
}

// ---------------------------------------------------------------------------
// GEMM: C[m][n] = sum_k A[m][k]*W[k][n]. M=512, K=2048, N=ncols. A,W f32.
// BM x 128 tile, 4 waves (2x2). R11: DEPTH-2 k-ring — two named register sets
// (rule #20: static indexing), loads for step ks+2 issued during step ks.
// mode 0 (qkv, BM=32): n<2048 -> qws (bf16*QSCALE); 2048..4095 -> kout tail;
// >=4096 -> vout tail. mode 1 (proj, BM=32): f32 yout[512][2048].
// ---------------------------------------------------------------------------
constexpr float QSCALE = 0.08838834764831845f * 1.4426950408889634f; // 1/sqrt(128)*log2e

template <int BM>
__global__ __launch_bounds__(256) void gemm_kernel(
    const float* __restrict__ A, const float* __restrict__ W,
    int ncols, int mode,
    unsigned short* __restrict__ qws, float* __restrict__ kout,
    float* __restrict__ vout, float* __restrict__ yout)
{
  constexpr int MI = BM / 32;
  constexpr int AIT = BM / 32;
  __shared__ __align__(16) unsigned short Alds[BM][72];
  __shared__ __align__(16) unsigned short Blds[128][72];

  const int tid = threadIdx.x;
  const int w = tid >> 6, l = tid & 63;
  const int lr = l & 15, lg = l >> 4;
  const int n0 = blockIdx.x * 128;
  const int m0 = blockIdx.y * BM;
  const int wm = (w >> 1) * (BM / 2), wn = (w & 1) * 64;

  const int arow = tid >> 3, acol = (tid & 7) << 3;
  const int bkp = tid >> 4, bcol = (tid & 15) << 3;
  const int bswz = ((bcol >> 3) & 7) << 3;

  f32x4 arA[AIT][2], arB[AIT][2];
  f32x4 brA[2][4], brB[2][4];

  auto loadA = [&](int k0, f32x4 (&ar)[AIT][2]) {
#pragma unroll
    for (int it = 0; it < AIT; ++it) {
      const float* pa = A + (size_t)(m0 + it * 32 + arow) * 2048 + k0 + acol;
      ar[it][0] = *(const f32x4*)pa;
      ar[it][1] = *(const f32x4*)(pa + 4);
    }
  };
  auto loadB = [&](int k0, f32x4 (&br)[2][4]) {
#pragma unroll
    for (int i = 0; i < 2; ++i) {
      const int krow = 2 * (i * 16 + bkp);
      const float* pw = W + (size_t)(k0 + krow) * ncols + n0 + bcol;
      br[i][0] = *(const f32x4*)pw;
      br[i][1] = *(const f32x4*)(pw + 4);
      br[i][2] = *(const f32x4*)(pw + ncols);
      br[i][3] = *(const f32x4*)(pw + ncols + 4);
    }
  };

  f32x4 acc[MI][4] = {};

  auto step = [&](int ks, f32x4 (&ar)[AIT][2], f32x4 (&br)[2][4]) {
    // regs -> LDS (bf16); implicit counted vmcnt waits only on this set
#pragma unroll
    for (int it = 0; it < AIT; ++it) {
      u32x4 p;
      p[0] = pack2(ar[it][0][0], ar[it][0][1]); p[1] = pack2(ar[it][0][2], ar[it][0][3]);
      p[2] = pack2(ar[it][1][0], ar[it][1][1]); p[3] = pack2(ar[it][1][2], ar[it][1][3]);
      *(u32x4*)(&Alds[it * 32 + arow][acol]) = p;
    }
#pragma unroll
    for (int i = 0; i < 2; ++i) {
      const int krow = 2 * (i * 16 + bkp);
      const int kc = krow ^ bswz;
#pragma unroll
      for (int j = 0; j < 8; ++j) {
        const float v0 = (j < 4) ? br[i][0][j] : br[i][1][j - 4];
        const float v1 = (j < 4) ? br[i][2][j] : br[i][3][j - 4];
        *(unsigned int*)(&Blds[bcol + j][kc]) = pack2(v0, v1);
      }
    }
    lds_barrier();

    if (ks + 2 < 32) { loadA((ks + 2) * 64, ar); loadB((ks + 2) * 64, br); } // 2 periods ahead

    s16x8 af[MI][2], bfr[4][2];
#pragma unroll
    for (int mi = 0; mi < MI; ++mi)
#pragma unroll
      for (int kk = 0; kk < 2; ++kk)
        af[mi][kk] = *(const s16x8*)(&Alds[wm + mi * 16 + lr][kk * 32 + lg * 8]);
#pragma unroll
    for (int ni = 0; ni < 4; ++ni) {
      const int n = wn + ni * 16 + lr;
      const int nswz = ((n >> 3) & 7) << 3;
#pragma unroll
      for (int kk = 0; kk < 2; ++kk)
        bfr[ni][kk] = *(const s16x8*)(&Blds[n][(kk * 32 + lg * 8) ^ nswz]);
    }
#pragma unroll
    for (int kk = 0; kk < 2; ++kk)
#pragma unroll
      for (int mi = 0; mi < MI; ++mi)
#pragma unroll
        for (int ni = 0; ni < 4; ++ni)
          acc[mi][ni] = MFMA_BF16(af[mi][kk], bfr[ni][kk], acc[mi][ni]);
    lds_barrier();
  };

  loadA(0, arA); loadB(0, brA);
  loadA(64, arB); loadB(64, brB);
  for (int ks = 0; ks < 32; ks += 2) {
    step(ks, arA, brA);
    step(ks + 1, arB, brB);
  }

  if (mode == 0) {
    const int which = n0 >> 11;
    const int h = (n0 >> 7) & 15;
    float* kv = (which == 1) ? kout : vout;
#pragma unroll
    for (int mi = 0; mi < MI; ++mi)
#pragma unroll
      for (int ni = 0; ni < 4; ++ni) {
        const int d = wn + ni * 16 + lr;
#pragma unroll
        for (int r = 0; r < 4; ++r) {
          const int mg = m0 + wm + mi * 16 + lg * 4 + r;
          const int b = mg >> 6, t = mg & 63;
          const float val = acc[mi][ni][r];
          if (which == 0)
            qws[(((size_t)(b * 16 + h) * 64 + t) << 7) + d] = f2bf(val * QSCALE);
          else
            kv[((size_t)(b * 16 + h) * 4160 + 4096 + t) * 128 + d] = val;
        }
      }
  } else {
#pragma unroll
    for (int mi = 0; mi < MI; ++mi)
#pragma unroll
      for (int ni = 0; ni < 4; ++ni) {
        const int n = n0 + wn + ni * 16 + lr;
#pragma unroll
        for (int r = 0; r < 4; ++r) {
          const int mg = m0 + wm + mi * 16 + lg * 4 + r;
          yout[(size_t)mg * 2048 + n] = acc[mi][ni][r];
        }
      }
  }
}

// ---------------------------------------------------------------------------
// Fused KV-cache copy + flash attention — R9 body, verbatim (best known).
// ---------------------------------------------------------------------------
__global__ __launch_bounds__(256, 4) void attn_kernel(
    const float* __restrict__ pastk, const float* __restrict__ pastv,
    const unsigned short* __restrict__ qws,
    float* __restrict__ kout, float* __restrict__ vout,
    float* __restrict__ Ows, float* __restrict__ mlws,
    int nseg, int seglen, int ntiles)
{
  __shared__ __align__(16) unsigned short Klds[32 * 128];
  __shared__ __align__(16) unsigned short VT[128 * 36];
  __shared__ __align__(16) unsigned short Plds[4 * 16 * 36];

  const int tid = threadIdx.x;
  const int w = tid >> 6, l = tid & 63;
  const int lr = l & 15, lg = l >> 4;
  const int bh = blockIdx.x / nseg;
  const int seg = blockIdx.x % nseg;
  const int segbase = seg * seglen;

  s16x8 qf[4];
  {
    const unsigned short* qb = qws + ((size_t)bh * 64 + w * 16 + lr) * 128 + lg * 8;
#pragma unroll
    for (int kk = 0; kk < 4; ++kk) qf[kk] = *(const s16x8*)(qb + kk * 32);
  }

  float mrow[4] = {-INFINITY, -INFINITY, -INFINITY, -INFINITY};
  float lrowv[4] = {0.f, 0.f, 0.f, 0.f};
  f32x4 Oacc[8] = {};

  const int skr = tid >> 3;
  const int sd = (tid & 7) << 2;
  const int kswz = (skr & 7) << 3;

  f32x4 kv[4], vv[4];
  int scur = 0; size_t oocur = 0;

  auto load_tile = [&](int t) {
    const int s = segbase + t * 32 + skr;
    const size_t oo = ((size_t)bh * 4160 + s) * 128 + sd;
    scur = s; oocur = oo;
    if (s < 4096) {
      const float* a = pastk + ((size_t)bh * 4096 + s) * 128 + sd;
      const float* b = pastv + ((size_t)bh * 4096 + s) * 128 + sd;
#pragma unroll
      for (int c = 0; c < 4; ++c) { kv[c] = *(const f32x4*)(a + 32 * c); vv[c] = *(const f32x4*)(b + 32 * c); }
    } else {
#pragma unroll
      for (int c = 0; c < 4; ++c) { kv[c] = *(const f32x4*)(kout + oo + 32 * c); vv[c] = *(const f32x4*)(vout + oo + 32 * c); }
    }
  };

  load_tile(0);
  for (int t = 0; t < ntiles; ++t) {
#pragma unroll
    for (int c = 0; c < 4; ++c) {
      const int d0 = sd + 32 * c;
      u32x2 pk;
      pk[0] = pack2(kv[c][0], kv[c][1]);
      pk[1] = pack2(kv[c][2], kv[c][3]);
      *(u32x2*)(&Klds[skr * 128 + (d0 ^ kswz)]) = pk;
#pragma unroll
      for (int e = 0; e < 4; ++e)
        VT[(d0 + e) * 36 + skr] = f2bf(vv[c][e]);
    }
    const bool dostore = (scur < 4096);
    const size_t oost = oocur;
    lds_barrier();

    if (dostore) {
      float* ko = kout + oost; float* vo = vout + oost;
#pragma unroll
      for (int c = 0; c < 4; ++c) { *(f32x4*)(ko + 32 * c) = kv[c]; *(f32x4*)(vo + 32 * c) = vv[c]; }
    }
    if (t + 1 < ntiles) load_tile(t + 1);

    f32x4 sc[2] = {};
#pragma unroll
    for (int kk = 0; kk < 4; ++kk)
#pragma unroll
      for (int st = 0; st < 2; ++st) {
        const int krow = st * 16 + lr;
        s16x8 kf = *(const s16x8*)(&Klds[krow * 128 + ((kk * 32 + lg * 8) ^ ((krow & 7) << 3))]);
        sc[st] = MFMA_BF16(qf[kk], kf, sc[st]);
      }

#pragma unroll
    for (int r = 0; r < 4; ++r) {
      float tm = fmaxf(sc[0][r], sc[1][r]);
      tm = fmaxf(tm, __shfl_xor(tm, 1));
      tm = fmaxf(tm, __shfl_xor(tm, 2));
      tm = fmaxf(tm, __shfl_xor(tm, 4));
      tm = fmaxf(tm, __shfl_xor(tm, 8));
      const float mn = fmaxf(mrow[r], tm);
      const float alpha = exp2f(mrow[r] - mn);
      mrow[r] = mn;
      const float p0f = exp2f(sc[0][r] - mn);
      const float p1f = exp2f(sc[1][r] - mn);
      float rs = p0f + p1f;
      rs += __shfl_xor(rs, 1);
      rs += __shfl_xor(rs, 2);
      rs += __shfl_xor(rs, 4);
      rs += __shfl_xor(rs, 8);
      lrowv[r] = lrowv[r] * alpha + rs;
#pragma unroll
      for (int dt = 0; dt < 8; ++dt) Oacc[dt][r] *= alpha;
      Plds[w * 576 + (lg * 4 + r) * 36 + lr] = f2bf(p0f);
      Plds[w * 576 + (lg * 4 + r) * 36 + 16 + lr] = f2bf(p1f);
    }

    const s16x4 plo = *(const s16x4*)(&Plds[w * 576 + lr * 36 + lg * 8]);
    const s16x4 phi = *(const s16x4*)(&Plds[w * 576 + lr * 36 + lg * 8 + 4]);
    const s16x8 pf = __builtin_shufflevector(plo, phi, 0, 1, 2, 3, 4, 5, 6, 7);
#pragma unroll
    for (int dt = 0; dt < 8; ++dt) {
      const int d = dt * 16 + lr;
      const s16x4 vlo = *(const s16x4*)(&VT[d * 36 + lg * 8]);
      const s16x4 vhi = *(const s16x4*)(&VT[d * 36 + lg * 8 + 4]);
      const s16x8 vf = __builtin_shufflevector(vlo, vhi, 0, 1, 2, 3, 4, 5, 6, 7);
      Oacc[dt] = MFMA_BF16(pf, vf, Oacc[dt]);
    }
    lds_barrier();
  }

  const size_t rowbase = ((size_t)seg * 128 + bh) * 64 + w * 16;
#pragma unroll
  for (int dt = 0; dt < 8; ++dt)
#pragma unroll
    for (int r = 0; r < 4; ++r)
      Ows[(rowbase + lg * 4 + r) * 128 + dt * 16 + lr] = Oacc[dt][r];
  if (lr == 0) {
#pragma unroll
    for (int r = 0; r < 4; ++r) {
      const size_t mi = rowbase + lg * 4 + r;
      mlws[mi * 2 + 0] = mrow[r];
      mlws[mi * 2 + 1] = lrowv[r];
    }
  }
}

// ---------------------------------------------------------------------------
// Merge NSEG partials -> yhead (unrolled).
// ---------------------------------------------------------------------------
template <int NSEG>
__global__ __launch_bounds__(256) void combine_kernel(
    const float* __restrict__ Ows, const float* __restrict__ mlws,
    float* __restrict__ yhead)
{
  const int idx = blockIdx.x * 256 + threadIdx.x;
  const int d4 = (idx & 31) << 2;
  const int row = idx >> 5;
  float M = -INFINITY;
#pragma unroll
  for (int s = 0; s < NSEG; ++s) M = fmaxf(M, mlws[((size_t)s * 8192 + row) * 2]);
  f32x4 num = {0.f, 0.f, 0.f, 0.f};
  float den = 0.f;
#pragma unroll
  for (int s = 0; s < NSEG; ++s) {
    const size_t r = (size_t)s * 8192 + row;
    const float wgt = exp2f(mlws[r * 2] - M);
    den += wgt * mlws[r * 2 + 1];
    const f32x4 o4 = *(const f32x4*)(Ows + r * 128 + d4);
#pragma unroll
    for (int e = 0; e < 4; ++e) num[e] += wgt * o4[e];
  }
  const float inv = 1.0f / den;
  const int bh = row >> 6, q = row & 63;
  const int b = bh >> 4, h = bh & 15;
  float* yp = yhead + (size_t)(b * 64 + q) * 2048 + h * 128 + d4;
#pragma unroll
  for (int e = 0; e < 4; ++e) yp[e] = num[e] * inv;
}

// ---------------------------------------------------------------------------
extern "C" void kernel_launch(void* const* d_in, const int* in_sizes, int n_in,
                              void* d_out, int out_size, void* d_ws, size_t ws_size,
                              hipStream_t stream)
{
  (void)in_sizes; (void)n_in; (void)out_size;
  const float* x  = (const float*)d_in[0];
  const float* pk = (const float*)d_in[1];
  const float* pv = (const float*)d_in[2];
  const float* wa = (const float*)d_in[3];
  const float* wp = (const float*)d_in[4];

  float* out  = (float*)d_out;
  float* y    = out;                          // 1,048,576
  float* kout = out + 1048576;                // 68,157,440
  float* vout = out + 1048576 + 68157440;     // 68,157,440

  char* ws = (char*)d_ws;
  unsigned short* qws = (unsigned short*)(ws);                      // 2 MiB bf16
  float* yhead = (float*)(ws + ((size_t)2 << 20));                  // 4 MiB f32
  float* mlws  = (float*)(ws + ((size_t)6 << 20));                  // 3 MiB (<=1.7 used)
  float* Ows   = (float*)(ws + ((size_t)9 << 20));                  // nseg*4 MiB

  const size_t base = (size_t)9 << 20;
  int nseg = 1;
  if (ws_size >= base + (size_t)26 * 4194304) nseg = 26;     // 3328 blocks
  else if (ws_size >= base + (size_t)10 * 4194304) nseg = 10;
  else if (ws_size >= base + (size_t)5 * 4194304) nseg = 5;
  const int seglen = 4160 / nseg;   // 160 / 416 / 832 / 4160
  const int ntiles = seglen / 32;

  gemm_kernel<32><<<dim3(48, 16), dim3(256), 0, stream>>>(x, wa, 6144, 0, qws, kout, vout, nullptr);
  attn_kernel<<<dim3(128 * nseg), dim3(256), 0, stream>>>(pk, pv, qws, kout, vout, Ows, mlws,
                                                          nseg, seglen, ntiles);
  if (nseg == 26)      combine_kernel<26><<<dim3(1024), dim3(256), 0, stream>>>(Ows, mlws, yhead);
  else if (nseg == 10) combine_kernel<10><<<dim3(1024), dim3(256), 0, stream>>>(Ows, mlws, yhead);
  else if (nseg == 5)  combine_kernel<5><<<dim3(1024), dim3(256), 0, stream>>>(Ows, mlws, yhead);
  else                 combine_kernel<1><<<dim3(1024), dim3(256), 0, stream>>>(Ows, mlws, yhead);
  gemm_kernel<32><<<dim3(16, 16), dim3(256), 0, stream>>>(yhead, wp, 2048, 1, nullptr, nullptr, nullptr, y);
}

// Round 12
// 353.307 us; speedup vs baseline: 5.6774x; 1.0478x over previous
//
#include <hip/hip_runtime.h>
#include <math.h>

// CausalSelfAttention w/ KV cache, MI355X gfx950.
// B=8 T=64 C=2048 H=16 hd=128 S=4096 -> SKV=4160. All device I/O is FLOAT32.
// Internals: bf16 MFMA (16x16x32), f32 accumulate.
// R12: nseg 26->13 (R11's partials-traffic regression reverted). Real LDS
// conflict fix (R6's was algebra-wrong: row stride 256B = all rows bank 0,
// XOR<<3 permuted only banks 0-15 -> K write stayed 8-way):
//   K: full-row XOR  d ^ ((k&7)<<4)  -> write/read ~2-way (free).
//   VT/Plds: stride 36->34 ush (17 dw, odd, coprime 32) -> scalar writes
//   spread across all banks (~2-way), b64 reads ~4-way.
// GEMM: depth-2 k-ring kept from R11.

typedef __attribute__((ext_vector_type(4))) float f32x4;
typedef __attribute__((ext_vector_type(8))) short s16x8;
typedef __attribute__((ext_vector_type(4))) short s16x4;
typedef __attribute__((ext_vector_type(2))) unsigned int u32x2;
typedef __attribute__((ext_vector_type(4))) unsigned int u32x4;

#define MFMA_BF16(A_, B_, C_) __builtin_amdgcn_mfma_f32_16x16x32_bf16((A_), (B_), (C_), 0, 0, 0)

__device__ __forceinline__ unsigned short f2bf(float f) {
  unsigned int u = __builtin_bit_cast(unsigned int, f);
  u += 0x7FFFu + ((u >> 16) & 1u);
  return (unsigned short)(u >> 16);
}
__device__ __forceinline__ unsigned int pack2(float a, float b) {
  return (unsigned int)f2bf(a) | ((unsigned int)f2bf(b) << 16);
}
// Barrier with LDS-visibility only: does NOT drain vmcnt.
__device__ __forceinline__ void lds_barrier() {
  asm volatile("s_waitcnt lgkmcnt(0)" ::: "memory");
  __builtin_amdgcn_s_barrier();
}

// ---------------------------------------------------------------------------
// GEMM (R11 depth-2 ring). BM x 128 tile, 4 waves.
// ---------------------------------------------------------------------------
constexpr float QSCALE = 0.08838834764831845f * 1.4426950408889634f; // 1/sqrt(128)*log2e

template <int BM>
__global__ __launch_bounds__(256) void gemm_kernel(
    const float* __restrict__ A, const float* __restrict__ W,
    int ncols, int mode,
    unsigned short* __restrict__ qws, float* __restrict__ kout,
    float* __restrict__ vout, float* __restrict__ yout)
{
  constexpr int MI = BM / 32;
  constexpr int AIT = BM / 32;
  __shared__ __align__(16) unsigned short Alds[BM][72];
  __shared__ __align__(16) unsigned short Blds[128][72];

  const int tid = threadIdx.x;
  const int w = tid >> 6, l = tid & 63;
  const int lr = l & 15, lg = l >> 4;
  const int n0 = blockIdx.x * 128;
  const int m0 = blockIdx.y * BM;
  const int wm = (w >> 1) * (BM / 2), wn = (w & 1) * 64;

  const int arow = tid >> 3, acol = (tid & 7) << 3;
  const int bkp = tid >> 4, bcol = (tid & 15) << 3;
  const int bswz = ((bcol >> 3) & 7) << 3;

  f32x4 arA[AIT][2], arB[AIT][2];
  f32x4 brA[2][4], brB[2][4];

  auto loadA = [&](int k0, f32x4 (&ar)[AIT][2]) {
#pragma unroll
    for (int it = 0; it < AIT; ++it) {
      const float* pa = A + (size_t)(m0 + it * 32 + arow) * 2048 + k0 + acol;
      ar[it][0] = *(const f32x4*)pa;
      ar[it][1] = *(const f32x4*)(pa + 4);
    }
  };
  auto loadB = [&](int k0, f32x4 (&br)[2][4]) {
#pragma unroll
    for (int i = 0; i < 2; ++i) {
      const int krow = 2 * (i * 16 + bkp);
      const float* pw = W + (size_t)(k0 + krow) * ncols + n0 + bcol;
      br[i][0] = *(const f32x4*)pw;
      br[i][1] = *(const f32x4*)(pw + 4);
      br[i][2] = *(const f32x4*)(pw + ncols);
      br[i][3] = *(const f32x4*)(pw + ncols + 4);
    }
  };

  f32x4 acc[MI][4] = {};

  auto step = [&](int ks, f32x4 (&ar)[AIT][2], f32x4 (&br)[2][4]) {
#pragma unroll
    for (int it = 0; it < AIT; ++it) {
      u32x4 p;
      p[0] = pack2(ar[it][0][0], ar[it][0][1]); p[1] = pack2(ar[it][0][2], ar[it][0][3]);
      p[2] = pack2(ar[it][1][0], ar[it][1][1]); p[3] = pack2(ar[it][1][2], ar[it][1][3]);
      *(u32x4*)(&Alds[it * 32 + arow][acol]) = p;
    }
#pragma unroll
    for (int i = 0; i < 2; ++i) {
      const int krow = 2 * (i * 16 + bkp);
      const int kc = krow ^ bswz;
#pragma unroll
      for (int j = 0; j < 8; ++j) {
        const float v0 = (j < 4) ? br[i][0][j] : br[i][1][j - 4];
        const float v1 = (j < 4) ? br[i][2][j] : br[i][3][j - 4];
        *(unsigned int*)(&Blds[bcol + j][kc]) = pack2(v0, v1);
      }
    }
    lds_barrier();

    if (ks + 2 < 32) { loadA((ks + 2) * 64, ar); loadB((ks + 2) * 64, br); }

    s16x8 af[MI][2], bfr[4][2];
#pragma unroll
    for (int mi = 0; mi < MI; ++mi)
#pragma unroll
      for (int kk = 0; kk < 2; ++kk)
        af[mi][kk] = *(const s16x8*)(&Alds[wm + mi * 16 + lr][kk * 32 + lg * 8]);
#pragma unroll
    for (int ni = 0; ni < 4; ++ni) {
      const int n = wn + ni * 16 + lr;
      const int nswz = ((n >> 3) & 7) << 3;
#pragma unroll
      for (int kk = 0; kk < 2; ++kk)
        bfr[ni][kk] = *(const s16x8*)(&Blds[n][(kk * 32 + lg * 8) ^ nswz]);
    }
#pragma unroll
    for (int kk = 0; kk < 2; ++kk)
#pragma unroll
      for (int mi = 0; mi < MI; ++mi)
#pragma unroll
        for (int ni = 0; ni < 4; ++ni)
          acc[mi][ni] = MFMA_BF16(af[mi][kk], bfr[ni][kk], acc[mi][ni]);
    lds_barrier();
  };

  loadA(0, arA); loadB(0, brA);
  loadA(64, arB); loadB(64, brB);
  for (int ks = 0; ks < 32; ks += 2) {
    step(ks, arA, brA);
    step(ks + 1, arB, brB);
  }

  if (mode == 0) {
    const int which = n0 >> 11;
    const int h = (n0 >> 7) & 15;
    float* kv = (which == 1) ? kout : vout;
#pragma unroll
    for (int mi = 0; mi < MI; ++mi)
#pragma unroll
      for (int ni = 0; ni < 4; ++ni) {
        const int d = wn + ni * 16 + lr;
#pragma unroll
        for (int r = 0; r < 4; ++r) {
          const int mg = m0 + wm + mi * 16 + lg * 4 + r;
          const int b = mg >> 6, t = mg & 63;
          const float val = acc[mi][ni][r];
          if (which == 0)
            qws[(((size_t)(b * 16 + h) * 64 + t) << 7) + d] = f2bf(val * QSCALE);
          else
            kv[((size_t)(b * 16 + h) * 4160 + 4096 + t) * 128 + d] = val;
        }
      }
  } else {
#pragma unroll
    for (int mi = 0; mi < MI; ++mi)
#pragma unroll
      for (int ni = 0; ni < 4; ++ni) {
        const int n = n0 + wn + ni * 16 + lr;
#pragma unroll
        for (int r = 0; r < 4; ++r) {
          const int mg = m0 + wm + mi * 16 + lg * 4 + r;
          yout[(size_t)mg * 2048 + n] = acc[mi][ni][r];
        }
      }
  }
}

// ---------------------------------------------------------------------------
// Fused KV-cache copy + flash attention. R9 structure; R12 LDS layouts:
//   Klds [32][128], swizzle d ^ ((k&7)<<4)   (full-row XOR, 2-way free)
//   VT   [128][34]  (17-dw odd stride)
//   Plds [4][16][34]
// ---------------------------------------------------------------------------
__global__ __launch_bounds__(256, 4) void attn_kernel(
    const float* __restrict__ pastk, const float* __restrict__ pastv,
    const unsigned short* __restrict__ qws,
    float* __restrict__ kout, float* __restrict__ vout,
    float* __restrict__ Ows, float* __restrict__ mlws,
    int nseg, int seglen, int ntiles)
{
  __shared__ __align__(16) unsigned short Klds[32 * 128];
  __shared__ __align__(16) unsigned short VT[128 * 34];
  __shared__ __align__(16) unsigned short Plds[4 * 16 * 34];

  const int tid = threadIdx.x;
  const int w = tid >> 6, l = tid & 63;
  const int lr = l & 15, lg = l >> 4;
  const int bh = blockIdx.x / nseg;
  const int seg = blockIdx.x % nseg;
  const int segbase = seg * seglen;

  s16x8 qf[4];
  {
    const unsigned short* qb = qws + ((size_t)bh * 64 + w * 16 + lr) * 128 + lg * 8;
#pragma unroll
    for (int kk = 0; kk < 4; ++kk) qf[kk] = *(const s16x8*)(qb + kk * 32);
  }

  float mrow[4] = {-INFINITY, -INFINITY, -INFINITY, -INFINITY};
  float lrowv[4] = {0.f, 0.f, 0.f, 0.f};
  f32x4 Oacc[8] = {};

  const int skr = tid >> 3;          // key row in tile (0..31)
  const int sd = (tid & 7) << 2;     // lane covers floats sd+32c+{0..3}
  const int kswz = (skr & 7) << 4;   // full-row XOR swizzle (ushort units)

  f32x4 kv[4], vv[4];
  int scur = 0; size_t oocur = 0;

  auto load_tile = [&](int t) {
    const int s = segbase + t * 32 + skr;
    const size_t oo = ((size_t)bh * 4160 + s) * 128 + sd;
    scur = s; oocur = oo;
    if (s < 4096) {
      const float* a = pastk + ((size_t)bh * 4096 + s) * 128 + sd;
      const float* b = pastv + ((size_t)bh * 4096 + s) * 128 + sd;
#pragma unroll
      for (int c = 0; c < 4; ++c) { kv[c] = *(const f32x4*)(a + 32 * c); vv[c] = *(const f32x4*)(b + 32 * c); }
    } else {
#pragma unroll
      for (int c = 0; c < 4; ++c) { kv[c] = *(const f32x4*)(kout + oo + 32 * c); vv[c] = *(const f32x4*)(vout + oo + 32 * c); }
    }
  };

  load_tile(0);
  for (int t = 0; t < ntiles; ++t) {
#pragma unroll
    for (int c = 0; c < 4; ++c) {
      const int d0 = sd + 32 * c;
      u32x2 pk;
      pk[0] = pack2(kv[c][0], kv[c][1]);
      pk[1] = pack2(kv[c][2], kv[c][3]);
      *(u32x2*)(&Klds[skr * 128 + (d0 ^ kswz)]) = pk;
#pragma unroll
      for (int e = 0; e < 4; ++e)
        VT[(d0 + e) * 34 + skr] = f2bf(vv[c][e]);
    }
    const bool dostore = (scur < 4096);
    const size_t oost = oocur;
    lds_barrier();

    if (dostore) {
      float* ko = kout + oost; float* vo = vout + oost;
#pragma unroll
      for (int c = 0; c < 4; ++c) { *(f32x4*)(ko + 32 * c) = kv[c]; *(f32x4*)(vo + 32 * c) = vv[c]; }
    }
    if (t + 1 < ntiles) load_tile(t + 1);

    f32x4 sc[2] = {};
#pragma unroll
    for (int kk = 0; kk < 4; ++kk)
#pragma unroll
      for (int st = 0; st < 2; ++st) {
        const int krow = st * 16 + lr;
        s16x8 kf = *(const s16x8*)(&Klds[krow * 128 + ((kk * 32 + lg * 8) ^ ((krow & 7) << 4))]);
        sc[st] = MFMA_BF16(qf[kk], kf, sc[st]);
      }

#pragma unroll
    for (int r = 0; r < 4; ++r) {
      float tm = fmaxf(sc[0][r], sc[1][r]);
      tm = fmaxf(tm, __shfl_xor(tm, 1));
      tm = fmaxf(tm, __shfl_xor(tm, 2));
      tm = fmaxf(tm, __shfl_xor(tm, 4));
      tm = fmaxf(tm, __shfl_xor(tm, 8));
      const float mn = fmaxf(mrow[r], tm);
      const float alpha = exp2f(mrow[r] - mn);
      mrow[r] = mn;
      const float p0f = exp2f(sc[0][r] - mn);
      const float p1f = exp2f(sc[1][r] - mn);
      float rs = p0f + p1f;
      rs += __shfl_xor(rs, 1);
      rs += __shfl_xor(rs, 2);
      rs += __shfl_xor(rs, 4);
      rs += __shfl_xor(rs, 8);
      lrowv[r] = lrowv[r] * alpha + rs;
#pragma unroll
      for (int dt = 0; dt < 8; ++dt) Oacc[dt][r] *= alpha;
      Plds[w * 544 + (lg * 4 + r) * 34 + lr] = f2bf(p0f);
      Plds[w * 544 + (lg * 4 + r) * 34 + 16 + lr] = f2bf(p1f);
    }

    const s16x4 plo = *(const s16x4*)(&Plds[w * 544 + lr * 34 + lg * 8]);
    const s16x4 phi = *(const s16x4*)(&Plds[w * 544 + lr * 34 + lg * 8 + 4]);
    const s16x8 pf = __builtin_shufflevector(plo, phi, 0, 1, 2, 3, 4, 5, 6, 7);
#pragma unroll
    for (int dt = 0; dt < 8; ++dt) {
      const int d = dt * 16 + lr;
      const s16x4 vlo = *(const s16x4*)(&VT[d * 34 + lg * 8]);
      const s16x4 vhi = *(const s16x4*)(&VT[d * 34 + lg * 8 + 4]);
      const s16x8 vf = __builtin_shufflevector(vlo, vhi, 0, 1, 2, 3, 4, 5, 6, 7);
      Oacc[dt] = MFMA_BF16(pf, vf, Oacc[dt]);
    }
    lds_barrier();
  }

  const size_t rowbase = ((size_t)seg * 128 + bh) * 64 + w * 16;
#pragma unroll
  for (int dt = 0; dt < 8; ++dt)
#pragma unroll
    for (int r = 0; r < 4; ++r)
      Ows[(rowbase + lg * 4 + r) * 128 + dt * 16 + lr] = Oacc[dt][r];
  if (lr == 0) {
#pragma unroll
    for (int r = 0; r < 4; ++r) {
      const size_t mi = rowbase + lg * 4 + r;
      mlws[mi * 2 + 0] = mrow[r];
      mlws[mi * 2 + 1] = lrowv[r];
    }
  }
}

// ---------------------------------------------------------------------------
// Merge NSEG partials -> yhead (unrolled).
// ---------------------------------------------------------------------------
template <int NSEG>
__global__ __launch_bounds__(256) void combine_kernel(
    const float* __restrict__ Ows, const float* __restrict__ mlws,
    float* __restrict__ yhead)
{
  const int idx = blockIdx.x * 256 + threadIdx.x;
  const int d4 = (idx & 31) << 2;
  const int row = idx >> 5;
  float M = -INFINITY;
#pragma unroll
  for (int s = 0; s < NSEG; ++s) M = fmaxf(M, mlws[((size_t)s * 8192 + row) * 2]);
  f32x4 num = {0.f, 0.f, 0.f, 0.f};
  float den = 0.f;
#pragma unroll
  for (int s = 0; s < NSEG; ++s) {
    const size_t r = (size_t)s * 8192 + row;
    const float wgt = exp2f(mlws[r * 2] - M);
    den += wgt * mlws[r * 2 + 1];
    const f32x4 o4 = *(const f32x4*)(Ows + r * 128 + d4);
#pragma unroll
    for (int e = 0; e < 4; ++e) num[e] += wgt * o4[e];
  }
  const float inv = 1.0f / den;
  const int bh = row >> 6, q = row & 63;
  const int b = bh >> 4, h = bh & 15;
  float* yp = yhead + (size_t)(b * 64 + q) * 2048 + h * 128 + d4;
#pragma unroll
  for (int e = 0; e < 4; ++e) yp[e] = num[e] * inv;
}

// ---------------------------------------------------------------------------
extern "C" void kernel_launch(void* const* d_in, const int* in_sizes, int n_in,
                              void* d_out, int out_size, void* d_ws, size_t ws_size,
                              hipStream_t stream)
{
  (void)in_sizes; (void)n_in; (void)out_size;
  const float* x  = (const float*)d_in[0];
  const float* pk = (const float*)d_in[1];
  const float* pv = (const float*)d_in[2];
  const float* wa = (const float*)d_in[3];
  const float* wp = (const float*)d_in[4];

  float* out  = (float*)d_out;
  float* y    = out;                          // 1,048,576
  float* kout = out + 1048576;                // 68,157,440
  float* vout = out + 1048576 + 68157440;     // 68,157,440

  char* ws = (char*)d_ws;
  unsigned short* qws = (unsigned short*)(ws);                      // 2 MiB bf16
  float* yhead = (float*)(ws + ((size_t)2 << 20));                  // 4 MiB f32
  float* mlws  = (float*)(ws + ((size_t)6 << 20));                  // <=852 KiB
  float* Ows   = (float*)(ws + ((size_t)7 << 20));                  // nseg*4 MiB

  const size_t base = (size_t)7 << 20;
  int nseg = 1;
  if (ws_size >= base + (size_t)13 * 4194304) nseg = 13;     // 1664 blocks
  else if (ws_size >= base + (size_t)5 * 4194304) nseg = 5;
  const int seglen = 4160 / nseg;   // 320 / 832 / 4160
  const int ntiles = seglen / 32;

  gemm_kernel<32><<<dim3(48, 16), dim3(256), 0, stream>>>(x, wa, 6144, 0, qws, kout, vout, nullptr);
  attn_kernel<<<dim3(128 * nseg), dim3(256), 0, stream>>>(pk, pv, qws, kout, vout, Ows, mlws,
                                                          nseg, seglen, ntiles);
  if (nseg == 13)      combine_kernel<13><<<dim3(1024), dim3(256), 0, stream>>>(Ows, mlws, yhead);
  else if (nseg == 5)  combine_kernel<5><<<dim3(1024), dim3(256), 0, stream>>>(Ows, mlws, yhead);
  else                 combine_kernel<1><<<dim3(1024), dim3(256), 0, stream>>>(Ows, mlws, yhead);
  gemm_kernel<32><<<dim3(16, 16), dim3(256), 0, stream>>>(yhead, wp, 2048, 1, nullptr, nullptr, nullptr, y);
}

// Round 13
// 339.270 us; speedup vs baseline: 5.9123x; 1.0414x over previous
//
#include <hip/hip_runtime.h>
#include <math.h>

// CausalSelfAttention w/ KV cache, MI355X gfx950.
// B=8 T=64 C=2048 H=16 hd=128 S=4096 -> SKV=4160. All device I/O is FLOAT32.
// Internals: bf16 MFMA (16x16x32), f32 accumulate.
// R13: WAVE-SPECIALIZED attn (producer-consumer). Waves 0-1 = loaders:
// stream K/V tiles (2 reg sets, loads-before-stores), write bf16 into
// double-buffered LDS + f32 cache-copy stores; they never sit in the compute
// chain. Waves 2-3 = computers (32 q each): QK/softmax/PV from LDS only.
// ONE lgkm-only barrier per tile (dbuf handoff). 3 blocks/CU.
// gemm = R5 depth-1 (best-known 344 config). nseg=13.

typedef __attribute__((ext_vector_type(4))) float f32x4;
typedef __attribute__((ext_vector_type(8))) short s16x8;
typedef __attribute__((ext_vector_type(4))) short s16x4;
typedef __attribute__((ext_vector_type(2))) unsigned int u32x2;
typedef __attribute__((ext_vector_type(4))) unsigned int u32x4;

#define MFMA_BF16(A_, B_, C_) __builtin_amdgcn_mfma_f32_16x16x32_bf16((A_), (B_), (C_), 0, 0, 0)

__device__ __forceinline__ unsigned short f2bf(float f) {
  unsigned int u = __builtin_bit_cast(unsigned int, f);
  u += 0x7FFFu + ((u >> 16) & 1u);
  return (unsigned short)(u >> 16);
}
__device__ __forceinline__ unsigned int pack2(float a, float b) {
  return (unsigned int)f2bf(a) | ((unsigned int)f2bf(b) << 16);
}
// Barrier with LDS-visibility only: does NOT drain vmcnt (loader stores/loads
// stay in flight across tiles).
__device__ __forceinline__ void lds_barrier() {
  asm volatile("s_waitcnt lgkmcnt(0)" ::: "memory");
  __builtin_amdgcn_s_barrier();
}

// ---------------------------------------------------------------------------
// GEMM (R5 depth-1, best-known). BM x 128 tile, 4 waves (2x2), k-step 64.
// mode 0 (qkv, BM=64): n<2048 -> qws (bf16*QSCALE, [B,H,T,hd]); 2048..4095 ->
// kout tail rows 4096..4159; >=4096 -> vout tail. mode 1 (proj, BM=32).
// ---------------------------------------------------------------------------
constexpr float QSCALE = 0.08838834764831845f * 1.4426950408889634f; // 1/sqrt(128)*log2e

template <int BM>
__global__ __launch_bounds__(256) void gemm_kernel(
    const float* __restrict__ A, const float* __restrict__ W,
    int ncols, int mode,
    unsigned short* __restrict__ qws, float* __restrict__ kout,
    float* __restrict__ vout, float* __restrict__ yout)
{
  constexpr int MI = BM / 32;
  constexpr int AIT = BM / 32;
  __shared__ __align__(16) unsigned short Alds[BM][72];
  __shared__ __align__(16) unsigned short Blds[128][72];

  const int tid = threadIdx.x;
  const int w = tid >> 6, l = tid & 63;
  const int lr = l & 15, lg = l >> 4;
  const int n0 = blockIdx.x * 128;
  const int m0 = blockIdx.y * BM;
  const int wm = (w >> 1) * (BM / 2), wn = (w & 1) * 64;

  const int arow = tid >> 3, acol = (tid & 7) << 3;
  const int bkp = tid >> 4, bcol = (tid & 15) << 3;
  const int bswz = ((bcol >> 3) & 7) << 3;

  f32x4 ar[AIT][2];
  f32x4 br[2][4];

  auto loadA = [&](int k0) {
#pragma unroll
    for (int it = 0; it < AIT; ++it) {
      const float* pa = A + (size_t)(m0 + it * 32 + arow) * 2048 + k0 + acol;
      ar[it][0] = *(const f32x4*)pa;
      ar[it][1] = *(const f32x4*)(pa + 4);
    }
  };
  auto loadB = [&](int k0) {
#pragma unroll
    for (int i = 0; i < 2; ++i) {
      const int krow = 2 * (i * 16 + bkp);
      const float* pw = W + (size_t)(k0 + krow) * ncols + n0 + bcol;
      br[i][0] = *(const f32x4*)pw;
      br[i][1] = *(const f32x4*)(pw + 4);
      br[i][2] = *(const f32x4*)(pw + ncols);
      br[i][3] = *(const f32x4*)(pw + ncols + 4);
    }
  };

  f32x4 acc[MI][4] = {};

  loadA(0); loadB(0);
  for (int ks = 0; ks < 32; ++ks) {
#pragma unroll
    for (int it = 0; it < AIT; ++it) {
      u32x4 p;
      p[0] = pack2(ar[it][0][0], ar[it][0][1]); p[1] = pack2(ar[it][0][2], ar[it][0][3]);
      p[2] = pack2(ar[it][1][0], ar[it][1][1]); p[3] = pack2(ar[it][1][2], ar[it][1][3]);
      *(u32x4*)(&Alds[it * 32 + arow][acol]) = p;
    }
#pragma unroll
    for (int i = 0; i < 2; ++i) {
      const int krow = 2 * (i * 16 + bkp);
      const int kc = krow ^ bswz;
#pragma unroll
      for (int j = 0; j < 8; ++j) {
        const float v0 = (j < 4) ? br[i][0][j] : br[i][1][j - 4];
        const float v1 = (j < 4) ? br[i][2][j] : br[i][3][j - 4];
        *(unsigned int*)(&Blds[bcol + j][kc]) = pack2(v0, v1);
      }
    }
    lds_barrier();

    if (ks < 31) { loadA((ks + 1) * 64); loadB((ks + 1) * 64); }

    s16x8 af[MI][2], bfr[4][2];
#pragma unroll
    for (int mi = 0; mi < MI; ++mi)
#pragma unroll
      for (int kk = 0; kk < 2; ++kk)
        af[mi][kk] = *(const s16x8*)(&Alds[wm + mi * 16 + lr][kk * 32 + lg * 8]);
#pragma unroll
    for (int ni = 0; ni < 4; ++ni) {
      const int n = wn + ni * 16 + lr;
      const int nswz = ((n >> 3) & 7) << 3;
#pragma unroll
      for (int kk = 0; kk < 2; ++kk)
        bfr[ni][kk] = *(const s16x8*)(&Blds[n][(kk * 32 + lg * 8) ^ nswz]);
    }
#pragma unroll
    for (int kk = 0; kk < 2; ++kk)
#pragma unroll
      for (int mi = 0; mi < MI; ++mi)
#pragma unroll
        for (int ni = 0; ni < 4; ++ni)
          acc[mi][ni] = MFMA_BF16(af[mi][kk], bfr[ni][kk], acc[mi][ni]);
    lds_barrier();
  }

  if (mode == 0) {
    const int which = n0 >> 11;
    const int h = (n0 >> 7) & 15;
    float* kv = (which == 1) ? kout : vout;
#pragma unroll
    for (int mi = 0; mi < MI; ++mi)
#pragma unroll
      for (int ni = 0; ni < 4; ++ni) {
        const int d = wn + ni * 16 + lr;
#pragma unroll
        for (int r = 0; r < 4; ++r) {
          const int mg = m0 + wm + mi * 16 + lg * 4 + r;
          const int b = mg >> 6, t = mg & 63;
          const float val = acc[mi][ni][r];
          if (which == 0)
            qws[(((size_t)(b * 16 + h) * 64 + t) << 7) + d] = f2bf(val * QSCALE);
          else
            kv[((size_t)(b * 16 + h) * 4160 + 4096 + t) * 128 + d] = val;
        }
      }
  } else {
#pragma unroll
    for (int mi = 0; mi < MI; ++mi)
#pragma unroll
      for (int ni = 0; ni < 4; ++ni) {
        const int n = n0 + wn + ni * 16 + lr;
#pragma unroll
        for (int r = 0; r < 4; ++r) {
          const int mg = m0 + wm + mi * 16 + lg * 4 + r;
          yout[(size_t)mg * 2048 + n] = acc[mi][ni][r];
        }
      }
  }
}

// ---------------------------------------------------------------------------
// Wave-specialized fused cache-copy + flash attention.
// Waves 0-1: loaders (128 threads): thread owns key-row skr=tid>>2, float cols
//   sd+16c (64B/row/instr coalesced). 2 reg sets; per tile: issue loads(t+1)
//   FIRST, then copy-stores(t), then convert(t+1)->LDS (counted vmcnt).
// Waves 2-3: computers, 32 q-rows each, LDS-only inner loop.
// LDS (dbuf): K[2][32][128] full-row-XOR; VT[2][128][40]; P[2 cw][32][40].
// One lds_barrier per tile. ntiles must be EVEN (130/26/10 all even).
// ---------------------------------------------------------------------------
__global__ __launch_bounds__(256) void attn_kernel(
    const float* __restrict__ pastk, const float* __restrict__ pastv,
    const unsigned short* __restrict__ qws,
    float* __restrict__ kout, float* __restrict__ vout,
    float* __restrict__ Ows, float* __restrict__ mlws,
    int nseg, int seglen, int ntiles)
{
  __shared__ __align__(16) unsigned short Klds[2][32 * 128];
  __shared__ __align__(16) unsigned short VT[2][128 * 40];
  __shared__ __align__(16) unsigned short Plds[2][32 * 40];

  const int tid = threadIdx.x;
  const int w = tid >> 6, l = tid & 63;
  const int lr = l & 15, lg = l >> 4;
  const int bh = blockIdx.x / nseg;
  const int seg = blockIdx.x % nseg;
  const int segbase = seg * seglen;

  if (w < 2) {
    // ============================ LOADER ============================
    const int skr = tid >> 2;          // key row 0..31
    const int sd = (tid & 3) << 2;     // float col start 0,4,8,12
    const int kswz = (skr & 7) << 4;   // full-row XOR (ushort units)

    f32x4 kvA[8], vvA[8], kvB[8], vvB[8];
    int sA = 0, sB = 0; size_t oA = 0, oB = 0;

    auto load_tile = [&](int t, f32x4 (&kv)[8], f32x4 (&vv)[8], int& sr, size_t& oor) {
      const int s = segbase + t * 32 + skr;
      const size_t oo = ((size_t)bh * 4160 + s) * 128 + sd;
      sr = s; oor = oo;
      if (s < 4096) {
        const float* a = pastk + ((size_t)bh * 4096 + s) * 128 + sd;
        const float* b = pastv + ((size_t)bh * 4096 + s) * 128 + sd;
#pragma unroll
        for (int c = 0; c < 8; ++c) { kv[c] = *(const f32x4*)(a + 16 * c); vv[c] = *(const f32x4*)(b + 16 * c); }
      } else {
#pragma unroll
        for (int c = 0; c < 8; ++c) { kv[c] = *(const f32x4*)(kout + oo + 16 * c); vv[c] = *(const f32x4*)(vout + oo + 16 * c); }
      }
    };
    auto store_tile = [&](const f32x4 (&kv)[8], const f32x4 (&vv)[8], int sr, size_t oo) {
      if (sr < 4096) {
        float* ko = kout + oo; float* vo = vout + oo;
#pragma unroll
        for (int c = 0; c < 8; ++c) { *(f32x4*)(ko + 16 * c) = kv[c]; *(f32x4*)(vo + 16 * c) = vv[c]; }
      }
    };
    auto convert_tile = [&](const f32x4 (&kv)[8], const f32x4 (&vv)[8], int buf) {
      unsigned short* Kb = Klds[buf];
      unsigned short* Vb = VT[buf];
#pragma unroll
      for (int c = 0; c < 8; ++c) {
        const int d0 = sd + 16 * c;
        u32x2 pk;
        pk[0] = pack2(kv[c][0], kv[c][1]);
        pk[1] = pack2(kv[c][2], kv[c][3]);
        *(u32x2*)(&Kb[skr * 128 + (d0 ^ kswz)]) = pk;
#pragma unroll
        for (int e = 0; e < 4; ++e)
          Vb[(d0 + e) * 40 + skr] = f2bf(vv[c][e]);
      }
    };

    load_tile(0, kvA, vvA, sA, oA);
    convert_tile(kvA, vvA, 0);
    lds_barrier();                       // buf0 ready

    for (int t = 0; t < ntiles; t += 2) {
      // tile t: computers read buf0; we prep buf1 (set B) and store set A.
      if (t + 1 < ntiles) load_tile(t + 1, kvB, vvB, sB, oB);   // loads FIRST
      store_tile(kvA, vvA, sA, oA);                             // stores float
      if (t + 1 < ntiles) convert_tile(kvB, vvB, 1);            // counted vmcnt
      lds_barrier();
      // tile t+1: computers read buf1; we prep buf0 (set A) and store set B.
      if (t + 1 < ntiles) {
        if (t + 2 < ntiles) load_tile(t + 2, kvA, vvA, sA, oA);
        store_tile(kvB, vvB, sB, oB);
        if (t + 2 < ntiles) convert_tile(kvA, vvA, 0);
        lds_barrier();
      }
    }
    // loaders done; computers wrote O/ml.
  } else {
    // =========================== COMPUTER ===========================
    const int cw = w - 2;                // 0,1
    unsigned short* Pw = Plds[cw];

    s16x8 qf[2][4];
#pragma unroll
    for (int qs = 0; qs < 2; ++qs) {
      const unsigned short* qb = qws + ((size_t)bh * 64 + cw * 32 + qs * 16 + lr) * 128 + lg * 8;
#pragma unroll
      for (int kk = 0; kk < 4; ++kk) qf[qs][kk] = *(const s16x8*)(qb + kk * 32);
    }

    float mrow[2][4], lrow[2][4];
#pragma unroll
    for (int qs = 0; qs < 2; ++qs)
#pragma unroll
      for (int r = 0; r < 4; ++r) { mrow[qs][r] = -INFINITY; lrow[qs][r] = 0.f; }
    f32x4 Oacc[2][8] = {};

    lds_barrier();                       // wait buf0

    for (int t = 0; t < ntiles; ++t) {
      const unsigned short* Kb = Klds[t & 1];
      const unsigned short* Vb = VT[t & 1];

      f32x4 sc[2][2] = {};               // [qs][st]
#pragma unroll
      for (int kk = 0; kk < 4; ++kk)
#pragma unroll
        for (int st = 0; st < 2; ++st) {
          const int krow = st * 16 + lr;
          s16x8 kf = *(const s16x8*)(&Kb[krow * 128 + ((kk * 32 + lg * 8) ^ ((krow & 7) << 4))]);
#pragma unroll
          for (int qs = 0; qs < 2; ++qs)
            sc[qs][st] = MFMA_BF16(qf[qs][kk], kf, sc[qs][st]);
        }

#pragma unroll
      for (int qs = 0; qs < 2; ++qs)
#pragma unroll
        for (int r = 0; r < 4; ++r) {
          float tm = fmaxf(sc[qs][0][r], sc[qs][1][r]);
          tm = fmaxf(tm, __shfl_xor(tm, 1));
          tm = fmaxf(tm, __shfl_xor(tm, 2));
          tm = fmaxf(tm, __shfl_xor(tm, 4));
          tm = fmaxf(tm, __shfl_xor(tm, 8));
          const float mn = fmaxf(mrow[qs][r], tm);
          const float alpha = exp2f(mrow[qs][r] - mn);
          mrow[qs][r] = mn;
          const float p0f = exp2f(sc[qs][0][r] - mn);
          const float p1f = exp2f(sc[qs][1][r] - mn);
          float rs = p0f + p1f;
          rs += __shfl_xor(rs, 1);
          rs += __shfl_xor(rs, 2);
          rs += __shfl_xor(rs, 4);
          rs += __shfl_xor(rs, 8);
          lrow[qs][r] = lrow[qs][r] * alpha + rs;
#pragma unroll
          for (int dt = 0; dt < 8; ++dt) Oacc[qs][dt][r] *= alpha;
          const int prow = qs * 16 + lg * 4 + r;
          Pw[prow * 40 + lr] = f2bf(p0f);
          Pw[prow * 40 + 16 + lr] = f2bf(p1f);
        }

      s16x8 pf[2];
#pragma unroll
      for (int qs = 0; qs < 2; ++qs) {
        const s16x4 plo = *(const s16x4*)(&Pw[(qs * 16 + lr) * 40 + lg * 8]);
        const s16x4 phi = *(const s16x4*)(&Pw[(qs * 16 + lr) * 40 + lg * 8 + 4]);
        pf[qs] = __builtin_shufflevector(plo, phi, 0, 1, 2, 3, 4, 5, 6, 7);
      }
#pragma unroll
      for (int dt = 0; dt < 8; ++dt) {
        const int d = dt * 16 + lr;
        const s16x4 vlo = *(const s16x4*)(&Vb[d * 40 + lg * 8]);
        const s16x4 vhi = *(const s16x4*)(&Vb[d * 40 + lg * 8 + 4]);
        const s16x8 vf = __builtin_shufflevector(vlo, vhi, 0, 1, 2, 3, 4, 5, 6, 7);
#pragma unroll
        for (int qs = 0; qs < 2; ++qs)
          Oacc[qs][dt] = MFMA_BF16(pf[qs], vf, Oacc[qs][dt]);
      }
      lds_barrier();
    }

    const size_t rowbase = ((size_t)seg * 128 + bh) * 64 + cw * 32;
#pragma unroll
    for (int qs = 0; qs < 2; ++qs)
#pragma unroll
      for (int dt = 0; dt < 8; ++dt)
#pragma unroll
        for (int r = 0; r < 4; ++r)
          Ows[(rowbase + qs * 16 + lg * 4 + r) * 128 + dt * 16 + lr] = Oacc[qs][dt][r];
    if (lr == 0) {
#pragma unroll
      for (int qs = 0; qs < 2; ++qs)
#pragma unroll
        for (int r = 0; r < 4; ++r) {
          const size_t mi = rowbase + qs * 16 + lg * 4 + r;
          mlws[mi * 2 + 0] = mrow[qs][r];
          mlws[mi * 2 + 1] = lrow[qs][r];
        }
    }
  }
}

// ---------------------------------------------------------------------------
// Merge NSEG partials -> yhead (unrolled).
// ---------------------------------------------------------------------------
template <int NSEG>
__global__ __launch_bounds__(256) void combine_kernel(
    const float* __restrict__ Ows, const float* __restrict__ mlws,
    float* __restrict__ yhead)
{
  const int idx = blockIdx.x * 256 + threadIdx.x;
  const int d4 = (idx & 31) << 2;
  const int row = idx >> 5;
  float M = -INFINITY;
#pragma unroll
  for (int s = 0; s < NSEG; ++s) M = fmaxf(M, mlws[((size_t)s * 8192 + row) * 2]);
  f32x4 num = {0.f, 0.f, 0.f, 0.f};
  float den = 0.f;
#pragma unroll
  for (int s = 0; s < NSEG; ++s) {
    const size_t r = (size_t)s * 8192 + row;
    const float wgt = exp2f(mlws[r * 2] - M);
    den += wgt * mlws[r * 2 + 1];
    const f32x4 o4 = *(const f32x4*)(Ows + r * 128 + d4);
#pragma unroll
    for (int e = 0; e < 4; ++e) num[e] += wgt * o4[e];
  }
  const float inv = 1.0f / den;
  const int bh = row >> 6, q = row & 63;
  const int b = bh >> 4, h = bh & 15;
  float* yp = yhead + (size_t)(b * 64 + q) * 2048 + h * 128 + d4;
#pragma unroll
  for (int e = 0; e < 4; ++e) yp[e] = num[e] * inv;
}

// ---------------------------------------------------------------------------
extern "C" void kernel_launch(void* const* d_in, const int* in_sizes, int n_in,
                              void* d_out, int out_size, void* d_ws, size_t ws_size,
                              hipStream_t stream)
{
  (void)in_sizes; (void)n_in; (void)out_size;
  const float* x  = (const float*)d_in[0];
  const float* pk = (const float*)d_in[1];
  const float* pv = (const float*)d_in[2];
  const float* wa = (const float*)d_in[3];
  const float* wp = (const float*)d_in[4];

  float* out  = (float*)d_out;
  float* y    = out;                          // 1,048,576
  float* kout = out + 1048576;                // 68,157,440
  float* vout = out + 1048576 + 68157440;     // 68,157,440

  char* ws = (char*)d_ws;
  unsigned short* qws = (unsigned short*)(ws);                      // 2 MiB bf16
  float* yhead = (float*)(ws + ((size_t)2 << 20));                  // 4 MiB f32
  float* mlws  = (float*)(ws + ((size_t)6 << 20));                  // <=852 KiB
  float* Ows   = (float*)(ws + ((size_t)7 << 20));                  // nseg*4 MiB

  const size_t base = (size_t)7 << 20;
  int nseg = 1;
  if (ws_size >= base + (size_t)13 * 4194304) nseg = 13;     // 1664 blocks
  else if (ws_size >= base + (size_t)5 * 4194304) nseg = 5;
  const int seglen = 4160 / nseg;   // 320 / 832 / 4160 -> ntiles 10/26/130 (even)
  const int ntiles = seglen / 32;

  gemm_kernel<64><<<dim3(48, 8), dim3(256), 0, stream>>>(x, wa, 6144, 0, qws, kout, vout, nullptr);
  attn_kernel<<<dim3(128 * nseg), dim3(256), 0, stream>>>(pk, pv, qws, kout, vout, Ows, mlws,
                                                          nseg, seglen, ntiles);
  if (nseg == 13)      combine_kernel<13><<<dim3(1024), dim3(256), 0, stream>>>(Ows, mlws, yhead);
  else if (nseg == 5)  combine_kernel<5><<<dim3(1024), dim3(256), 0, stream>>>(Ows, mlws, yhead);
  else                 combine_kernel<1><<<dim3(1024), dim3(256), 0, stream>>>(Ows, mlws, yhead);
  gemm_kernel<32><<<dim3(16, 16), dim3(256), 0, stream>>>(yhead, wp, 2048, 1, nullptr, nullptr, nullptr, y);
}